// Round 4
// baseline (180.901 us; speedup 1.0000x reference)
//
#include <hip/hip_runtime.h>
#include <cstddef>

#define NN 3072
#define RR 16
#define UNROLL 16

typedef float f32x4 __attribute__((ext_vector_type(4)));

// Prologue: key[i] = (cls not in {24,25,26}) ? batch[i] : -1
__global__ void frd_key_kernel(const int* __restrict__ cls,
                               const int* __restrict__ batch,
                               int* __restrict__ key) {
    int i = blockIdx.x * blockDim.x + threadIdx.x;
    if (i < NN) {
        int c = cls[i];
        bool valid = (c != 24) && (c != 25) && (c != 26);
        key[i] = valid ? batch[i] : -1;
    }
}

// Main: each thread handles UNROLL independent float4 quads of out [N, N, R].
// Phase 1 issues all UNROLL seg loads (16 outstanding VMEM reads), phase 2
// computes and streams the stores. Block covers 256*UNROLL contiguous quads
// (64 KB); each store instruction is a full 1 KB/wave coalesced burst.
__global__ __launch_bounds__(256)
void frd_main_kernel(const float* __restrict__ z1,
                     const float* __restrict__ z2,
                     const float* __restrict__ seg,
                     const int* __restrict__ key,
                     float* __restrict__ out) {
    const int base = blockIdx.x * (256 * UNROLL) + threadIdx.x;
    const float d0 = ((threadIdx.x & 3) == 0) ? 1.0f : 0.0f;  // one_hot(0,R) head

    // Phase 1: issue all seg loads up front (independent, 16 in flight).
    float segv[UNROLL];
#pragma unroll
    for (int k = 0; k < UNROLL; ++k) {
        const int idx = base + k * 256;
        segv[k] = __builtin_nontemporal_load(seg + (idx >> 2));
    }

    // Phase 2: compute + store.
#pragma unroll
    for (int k = 0; k < UNROLL; ++k) {
        const int idx = base + k * 256;
        const int pair = idx >> 2;
        const int q = idx & 3;
        const int i = pair / NN;          // magic-mul by compiler
        const int j = pair - i * NN;

        const int ki = key[i];            // L1-resident
        const int kj = key[j];
        // seg_eff = seg_matrix + eye; pair iff seg_eff == 0, keys match, valid
        const float seg_eff = segv[k] + ((i == j) ? 1.0f : 0.0f);
        const bool is_pair = (ki == kj) && (ki >= 0) && (seg_eff == 0.0f);

        // Unconditional loads — z1/z2 are 192 KB each, cache-resident.
        const float4 a = *reinterpret_cast<const float4*>(z1 + i * RR + q * 4);
        const float4 b = *reinterpret_cast<const float4*>(z2 + j * RR + q * 4);

        f32x4 r;
        r.x = is_pair ? a.x * b.x : d0;
        r.y = is_pair ? a.y * b.y : 0.0f;
        r.z = is_pair ? a.z * b.z : 0.0f;
        r.w = is_pair ? a.w * b.w : 0.0f;

        // Streaming write (604 MB, no reuse)
        __builtin_nontemporal_store(r, reinterpret_cast<f32x4*>(out + (size_t)idx * 4));
    }
}

extern "C" void kernel_launch(void* const* d_in, const int* in_sizes, int n_in,
                              void* d_out, int out_size, void* d_ws, size_t ws_size,
                              hipStream_t stream) {
    const float* z1  = (const float*)d_in[0];
    const float* z2  = (const float*)d_in[1];
    const float* seg = (const float*)d_in[2];
    const int* cls   = (const int*)d_in[3];
    const int* batch = (const int*)d_in[4];
    float* out = (float*)d_out;
    int* key = (int*)d_ws;

    frd_key_kernel<<<(NN + 255) / 256, 256, 0, stream>>>(cls, batch, key);

    const int total = NN * NN * 4;          // 37,748,736 = 9,216 * 256 * 16 exactly
    frd_main_kernel<<<total / (256 * UNROLL), 256, 0, stream>>>(z1, z2, seg, key, out);
}

// Round 5
// 143.083 us; speedup vs baseline: 1.2643x; 1.2643x over previous
//
#include <hip/hip_runtime.h>
#include <cstddef>

#define NN 3072
#define RR 16
#define UNROLL 8

typedef float f32x4 __attribute__((ext_vector_type(4)));

// Prologue: key[i] = (cls not in {24,25,26}) ? batch[i] : -1
__global__ void frd_key_kernel(const int* __restrict__ cls,
                               const int* __restrict__ batch,
                               int* __restrict__ key) {
    int i = blockIdx.x * blockDim.x + threadIdx.x;
    if (i < NN) {
        int c = cls[i];
        bool valid = (c != 24) && (c != 25) && (c != 26);
        key[i] = valid ? batch[i] : -1;
    }
}

// Main: each thread handles UNROLL independent float4 quads of out [N, N, R].
// Interleaved (R3 structure — compiler cycles a small register window).
// Block covers 256*UNROLL contiguous quads (32 KB); each store instruction is
// a full 1 KB/wave coalesced burst. Stores are REGULAR (non-NT) this round:
// A/B test of the nt flag's effect on TCC write-combining.
__global__ __launch_bounds__(256)
void frd_main_kernel(const float* __restrict__ z1,
                     const float* __restrict__ z2,
                     const float* __restrict__ seg,
                     const int* __restrict__ key,
                     float* __restrict__ out) {
    const int base = blockIdx.x * (256 * UNROLL) + threadIdx.x;
    const float d0 = ((threadIdx.x & 3) == 0) ? 1.0f : 0.0f;  // one_hot(0,R) head

#pragma unroll
    for (int k = 0; k < UNROLL; ++k) {
        const int idx = base + k * 256;
        const int pair = idx >> 2;
        const int q = idx & 3;
        const int i = pair / NN;          // magic-mul by compiler
        const int j = pair - i * NN;

        // seg index == i*N + j == pair; read-once stream -> NT load
        const float s = __builtin_nontemporal_load(seg + pair);
        const int ki = key[i];            // cache-resident
        const int kj = key[j];
        // seg_eff = seg_matrix + eye; pair iff seg_eff == 0, keys match, valid
        const float seg_eff = s + ((i == j) ? 1.0f : 0.0f);
        const bool is_pair = (ki == kj) && (ki >= 0) && (seg_eff == 0.0f);

        // Unconditional loads — z1/z2 are 192 KB each, cache-resident.
        const float4 a = *reinterpret_cast<const float4*>(z1 + i * RR + q * 4);
        const float4 b = *reinterpret_cast<const float4*>(z2 + j * RR + q * 4);

        f32x4 r;
        r.x = is_pair ? a.x * b.x : d0;
        r.y = is_pair ? a.y * b.y : 0.0f;
        r.z = is_pair ? a.z * b.z : 0.0f;
        r.w = is_pair ? a.w * b.w : 0.0f;

        // Regular store (A/B vs R3's nontemporal store)
        *reinterpret_cast<f32x4*>(out + (size_t)idx * 4) = r;
    }
}

extern "C" void kernel_launch(void* const* d_in, const int* in_sizes, int n_in,
                              void* d_out, int out_size, void* d_ws, size_t ws_size,
                              hipStream_t stream) {
    const float* z1  = (const float*)d_in[0];
    const float* z2  = (const float*)d_in[1];
    const float* seg = (const float*)d_in[2];
    const int* cls   = (const int*)d_in[3];
    const int* batch = (const int*)d_in[4];
    float* out = (float*)d_out;
    int* key = (int*)d_ws;

    frd_key_kernel<<<(NN + 255) / 256, 256, 0, stream>>>(cls, batch, key);

    const int total = NN * NN * 4;          // 37,748,736 = 18,432 * 256 * 8 exactly
    frd_main_kernel<<<total / (256 * UNROLL), 256, 0, stream>>>(z1, z2, seg, key, out);
}

// Round 6
// 135.461 us; speedup vs baseline: 1.3354x; 1.0563x over previous
//
#include <hip/hip_runtime.h>
#include <cstddef>

#define NN 3072
#define RR 16
#define UNROLL 8

typedef float f32x4 __attribute__((ext_vector_type(4)));

// ---------- Pass 1: predicate byte per pair ----------
// pred[pair] = node_mask[i] & node_mask[j] & (batch[i]==batch[j]) & (seg+eye==0)
__global__ __launch_bounds__(256)
void frd_pred_kernel(const float* __restrict__ seg,
                     const int* __restrict__ cls,
                     const int* __restrict__ batch,
                     unsigned char* __restrict__ pred) {
    const int pair = blockIdx.x * 256 + threadIdx.x;   // grid exact: N*N/256
    const int i = pair / NN;                            // magic-mul
    const int j = pair - i * NN;
    const float s = __builtin_nontemporal_load(seg + pair);
    const int ci = cls[i], cj = cls[j];                 // 12 KB, L1-resident
    const bool vi = (ci != 24) && (ci != 25) && (ci != 26);
    const bool vj = (cj != 24) && (cj != 25) && (cj != 26);
    const bool pb = batch[i] == batch[j];
    const float seg_eff = s + ((i == j) ? 1.0f : 0.0f);
    pred[pair] = (vi && vj && pb && (seg_eff == 0.0f)) ? 1 : 0;
}

// ---------- Pass 2: near-pure write sweep ----------
// Block (i, s6): i = bid/6 (wave-uniform scalar), covers row i, pairs
// [s6*512, s6*512+512). Thread (pin=tid>>2, q=tid&3) handles UNROLL quads at
// pair = i*NN + j0 + k*64. All addresses linear in k; lane l of a wave touches
// byte offset 16*l -> every load/store is a 1 KB contiguous wave burst.
__global__ __launch_bounds__(256)
void frd_main_kernel(const float* __restrict__ z1,
                     const float* __restrict__ z2,
                     const unsigned char* __restrict__ pred,
                     float* __restrict__ out) {
    const int bid = blockIdx.x;
    const int i = bid / 6;                   // scalar magic-div
    const int s6 = bid - i * 6;
    const int tid = threadIdx.x;
    const int q = tid & 3;
    const int pin = tid >> 2;                // [0,64)
    const int j0 = s6 * 512 + pin;

    // k-invariant values
    const float4 a = *reinterpret_cast<const float4*>(z1 + i * RR + q * 4);
    const float d0 = (q == 0) ? 1.0f : 0.0f;            // one_hot(0,R) head
    const unsigned char* pp = pred + i * NN + j0;       // +k*64 (imm)
    const float* bp = z2 + j0 * RR + q * 4;             // +k*1024 floats
    float* op = out + ((size_t)(i * NN + j0) * RR) + q * 4;  // +k*1024 floats

#pragma unroll
    for (int k = 0; k < UNROLL; ++k) {
        const unsigned char pv = pp[k * 64];            // broadcast, L2-resident
        const float4 b = *reinterpret_cast<const float4*>(bp + k * 1024);
        const bool m = pv != 0;
        f32x4 r;
        r.x = m ? a.x * b.x : d0;
        r.y = m ? a.y * b.y : 0.0f;
        r.z = m ? a.z * b.z : 0.0f;
        r.w = m ? a.w * b.w : 0.0f;
        __builtin_nontemporal_store(r, reinterpret_cast<f32x4*>(op + k * 1024));
    }
}

// ---------- Fallback (R3 structure) if ws too small for predicate ----------
__global__ void frd_key_kernel(const int* __restrict__ cls,
                               const int* __restrict__ batch,
                               int* __restrict__ key) {
    int i = blockIdx.x * blockDim.x + threadIdx.x;
    if (i < NN) {
        int c = cls[i];
        bool valid = (c != 24) && (c != 25) && (c != 26);
        key[i] = valid ? batch[i] : -1;
    }
}

__global__ __launch_bounds__(256)
void frd_fallback_kernel(const float* __restrict__ z1,
                         const float* __restrict__ z2,
                         const float* __restrict__ seg,
                         const int* __restrict__ key,
                         float* __restrict__ out) {
    const int base = blockIdx.x * (256 * UNROLL) + threadIdx.x;
    const float d0 = ((threadIdx.x & 3) == 0) ? 1.0f : 0.0f;
#pragma unroll
    for (int k = 0; k < UNROLL; ++k) {
        const int idx = base + k * 256;
        const int pair = idx >> 2;
        const int q = idx & 3;
        const int i = pair / NN;
        const int j = pair - i * NN;
        const float s = __builtin_nontemporal_load(seg + pair);
        const int ki = key[i];
        const int kj = key[j];
        const float seg_eff = s + ((i == j) ? 1.0f : 0.0f);
        const bool is_pair = (ki == kj) && (ki >= 0) && (seg_eff == 0.0f);
        const float4 a = *reinterpret_cast<const float4*>(z1 + i * RR + q * 4);
        const float4 b = *reinterpret_cast<const float4*>(z2 + j * RR + q * 4);
        f32x4 r;
        r.x = is_pair ? a.x * b.x : d0;
        r.y = is_pair ? a.y * b.y : 0.0f;
        r.z = is_pair ? a.z * b.z : 0.0f;
        r.w = is_pair ? a.w * b.w : 0.0f;
        __builtin_nontemporal_store(r, reinterpret_cast<f32x4*>(out + (size_t)idx * 4));
    }
}

extern "C" void kernel_launch(void* const* d_in, const int* in_sizes, int n_in,
                              void* d_out, int out_size, void* d_ws, size_t ws_size,
                              hipStream_t stream) {
    const float* z1  = (const float*)d_in[0];
    const float* z2  = (const float*)d_in[1];
    const float* seg = (const float*)d_in[2];
    const int* cls   = (const int*)d_in[3];
    const int* batch = (const int*)d_in[4];
    float* out = (float*)d_out;

    if (ws_size >= (size_t)NN * NN) {
        unsigned char* pred = (unsigned char*)d_ws;
        frd_pred_kernel<<<NN * NN / 256, 256, 0, stream>>>(seg, cls, batch, pred);
        frd_main_kernel<<<NN * 6 / 1 , 256, 0, stream>>>(z1, z2, pred, out);
        // grid = 3072 rows * 6 blocks/row = 18432; each block: 512 pairs * 4 quads
        // * ... = 256 threads * UNROLL(8) quads = 2048 quads = 512 pairs. exact.
    } else {
        int* key = (int*)d_ws;
        frd_key_kernel<<<(NN + 255) / 256, 256, 0, stream>>>(cls, batch, key);
        const int total = NN * NN * 4;
        frd_fallback_kernel<<<total / (256 * UNROLL), 256, 0, stream>>>(z1, z2, seg, key, out);
    }
}